// Round 3
// baseline (1416.874 us; speedup 1.0000x reference)
//
#include <hip/hip_runtime.h>
#include <hip/hip_bf16.h>

// R2 (still no bench — 3x GPU timeout). Changes vs R1, cost-model driven:
//  - feats GEMM -> 3x bf16-split MFMA (16x16x32, guide-verified layouts),
//    weights pre-packed into per-lane fragment order, staged in LDS (64KB).
//  - winner bias removed from hot kernel: uniform bp[o] bias folded into
//    accumulator init; tiny fixup kernel patches <=4096 winner cells after.
//  - gemm1/ucontrib unchanged (fp32); MFMA them next round once correct.

constexpr int T_ = 4, E_ = 4096, B_ = 2, D_ = 128, N_ = 384;
constexpr int EB = E_ * B_;                  // 8192 (e,b) pairs
constexpr int XSTRIDE_T = E_ * B_ * D_;      // 1048576 floats between t-planes
constexpr int NROWS = N_ * N_ * B_;          // 294912 feats rows
constexpr int NCELLS = N_ * N_;              // 147456

typedef __attribute__((ext_vector_type(8))) short bf16x8;
typedef __attribute__((ext_vector_type(4))) float f32x4;
union BF8 { bf16x8 v; ushort u[8]; };

// workspace layout (float element offsets)
constexpr size_t OFF_WTG   = 0;                              // 16384: W_g^T [d][o]
constexpr size_t OFF_WTL   = 16384;                          // 16384: W_comb left^T [c][o]
constexpr size_t OFF_WTR   = 32768;                          // 16384: W_comb right^T [c][o]
constexpr size_t OFF_BCOMB = 49152;                          // 128
constexpr size_t OFF_BP    = 49280;                          // 128
constexpr size_t OFF_XMEAN = 49408;                          // EB*D
constexpr size_t OFF_UC    = OFF_XMEAN + (size_t)EB * D_;    // EB*D
constexpr size_t OFF_WIN   = OFF_UC + (size_t)EB * D_;       // N*N ints
constexpr size_t OFF_BPACK = OFF_WIN + (size_t)NCELLS;       // 64KB = 16384 floats
constexpr size_t WS_FLOATS = OFF_BPACK + 16384;

static __device__ inline ushort f2bf(float x) {
  const uint u = __float_as_uint(x);
  return (ushort)((u + 0x7fffu + ((u >> 16) & 1u)) >> 16);
}
static __device__ inline float bf2f(ushort h) {
  return __uint_as_float(((uint)h) << 16);
}

// ---------------------------------------------------------------------------
// prep: W_comb halves (transposed), W_g transpose, bcomb, bp, winner init
// ---------------------------------------------------------------------------
__global__ __launch_bounds__(256) void prep_kernel(
    const float* __restrict__ W_f, const float* __restrict__ W_lin,
    const float* __restrict__ W_g, const float* __restrict__ b_lin,
    const float* __restrict__ b_f, const float* __restrict__ pad,
    float* __restrict__ WtG, float* __restrict__ WtL, float* __restrict__ WtR,
    float* __restrict__ bcomb, float* __restrict__ bp, int* __restrict__ winner) {
  const int o = blockIdx.x;    // 0..127
  const int c = threadIdx.x;   // 0..255

  for (int i = blockIdx.x * 256 + c; i < NCELLS; i += 128 * 256) winner[i] = -1;

  float acc = 0.f;
#pragma unroll 4
  for (int d = 0; d < D_; ++d) acc += W_f[o * D_ + d] * W_lin[d * (2 * D_) + c];

  if (c < D_) {
    WtL[c * D_ + o] = acc;
    WtG[c * D_ + o] = W_g[o * D_ + c];
  } else {
    WtR[(c - D_) * D_ + o] = acc;
  }

  __shared__ float red[256];
  red[c] = (c >= D_) ? acc : 0.f;
  __syncthreads();
  for (int s = 128; s > 0; s >>= 1) {
    if (c < s) red[c] += red[c + s];
    __syncthreads();
  }
  const float padsum = red[0];
  __syncthreads();
  red[c] = (c < D_) ? W_f[o * D_ + c] * b_lin[c] : 0.f;
  __syncthreads();
  for (int s = 128; s > 0; s >>= 1) {
    if (c < s) red[c] += red[c + s];
    __syncthreads();
  }
  if (c == 0) {
    const float bc = b_f[o] + red[0];
    bcomb[o] = bc;
    bp[o] = bc + pad[0] * padsum;
  }
}

// ---------------------------------------------------------------------------
// prep2: pack W_comb_left (bf16 hi/lo split) into MFMA 16x16x32 B-fragment
// per-lane order. Frag fi = hi*32 + k0*8 + n0 (64 frags x 64 lanes x 8 bf16).
// B[k][n] = WtL[k][n]; lane l: n = n0*16 + (l&15), k = k0*32 + (l>>4)*8 + j.
// grid: 64 blocks x 64 threads.
// ---------------------------------------------------------------------------
__global__ __launch_bounds__(64) void prep2_kernel(
    const float* __restrict__ WtL, ushort* __restrict__ Bpack) {
  const int fi = blockIdx.x;          // 0..63
  const int l = threadIdx.x;          // 0..63
  const int ishi = (fi >> 5) ^ 1;     // fi<32 -> hi
  const int k0 = (fi >> 3) & 3;
  const int n0 = fi & 7;
  const int o = n0 * 16 + (l & 15);
  const int kb = k0 * 32 + ((l >> 4) & 3) * 8;
  ushort* dst = Bpack + ((size_t)fi * 64 + l) * 8;
#pragma unroll
  for (int j = 0; j < 8; ++j) {
    const float w = WtL[(size_t)(kb + j) * D_ + o];
    const ushort h = f2bf(w);
    if (ishi) {
      dst[j] = h;
    } else {
      dst[j] = f2bf(w - bf2f(h));
    }
  }
}

// ---------------------------------------------------------------------------
// scatter: last-e-wins per grid cell (deterministic via atomicMax on e)
// ---------------------------------------------------------------------------
__global__ __launch_bounds__(256) void scatter_kernel(
    const int* __restrict__ nodes, int* __restrict__ winner) {
  const int e = blockIdx.x * 256 + threadIdx.x;
  if (e < E_) {
    const int n0 = nodes[e * 2 + 0];
    const int n1 = nodes[e * 2 + 1];
    atomicMax(&winner[(n0 - 1) * N_ + (n1 - 1)], e);
  }
}

// ---------------------------------------------------------------------------
// gemm1: out_x[t,e,b,o] = x[t,e,b,:].W_g[o,:] + b_g[o]; xmean = mean_t + b_g
// 512 thr = 8 waves, wave handles 8 (e,b) pairs, lane owns o2,o2+1. fp32.
// ---------------------------------------------------------------------------
__global__ __launch_bounds__(512, 4) void gemm1_kernel(
    const float* __restrict__ x, const float* __restrict__ WtG,
    const float* __restrict__ b_g, float* __restrict__ out_x,
    float* __restrict__ xmean) {
  __shared__ float lw[D_ * D_];
  const int tid = threadIdx.x;
  for (int i = tid * 4; i < D_ * D_; i += 2048)
    *(float4*)&lw[i] = *(const float4*)&WtG[i];
  __syncthreads();

  const int wave = tid >> 6, lane = tid & 63;
  const int o2 = lane * 2;
  const float2 bg = *(const float2*)&b_g[o2];

  for (int pp = 0; pp < 8; ++pp) {
    const int pair = blockIdx.x * 64 + wave * 8 + pp;
    const float* __restrict__ xr = x + (size_t)pair * D_;  // t=0 row
    float ax[4] = {0, 0, 0, 0}, ay[4] = {0, 0, 0, 0};
    float4 a[4], b4[4];
#pragma unroll
    for (int t = 0; t < 4; ++t)
      a[t] = *(const float4*)&xr[t * XSTRIDE_T + 0];
#pragma unroll
    for (int dd = 0; dd < D_; dd += 8) {
#pragma unroll
      for (int t = 0; t < 4; ++t)
        b4[t] = *(const float4*)&xr[t * XSTRIDE_T + dd + 4];
      {
        const float2 w0 = *(const float2*)&lw[(dd + 0) * D_ + o2];
        const float2 w1 = *(const float2*)&lw[(dd + 1) * D_ + o2];
        const float2 w2 = *(const float2*)&lw[(dd + 2) * D_ + o2];
        const float2 w3 = *(const float2*)&lw[(dd + 3) * D_ + o2];
#pragma unroll
        for (int t = 0; t < 4; ++t) {
          ax[t] += a[t].x * w0.x; ay[t] += a[t].x * w0.y;
          ax[t] += a[t].y * w1.x; ay[t] += a[t].y * w1.y;
          ax[t] += a[t].z * w2.x; ay[t] += a[t].z * w2.y;
          ax[t] += a[t].w * w3.x; ay[t] += a[t].w * w3.y;
        }
      }
      if (dd + 8 < D_) {
#pragma unroll
        for (int t = 0; t < 4; ++t)
          a[t] = *(const float4*)&xr[t * XSTRIDE_T + dd + 8];
      }
      {
        const float2 w0 = *(const float2*)&lw[(dd + 4) * D_ + o2];
        const float2 w1 = *(const float2*)&lw[(dd + 5) * D_ + o2];
        const float2 w2 = *(const float2*)&lw[(dd + 6) * D_ + o2];
        const float2 w3 = *(const float2*)&lw[(dd + 7) * D_ + o2];
#pragma unroll
        for (int t = 0; t < 4; ++t) {
          ax[t] += b4[t].x * w0.x; ay[t] += b4[t].x * w0.y;
          ax[t] += b4[t].y * w1.x; ay[t] += b4[t].y * w1.y;
          ax[t] += b4[t].z * w2.x; ay[t] += b4[t].z * w2.y;
          ax[t] += b4[t].w * w3.x; ay[t] += b4[t].w * w3.y;
        }
      }
    }
    const size_t obase = (size_t)pair * D_ + o2;
#pragma unroll
    for (int t = 0; t < 4; ++t)
      *(float2*)&out_x[obase + (size_t)t * XSTRIDE_T] =
          make_float2(ax[t] + bg.x, ay[t] + bg.y);
    *(float2*)&xmean[(size_t)pair * D_ + o2] =
        make_float2((ax[0] + ax[1] + ax[2] + ax[3]) * 0.25f + bg.x,
                    (ay[0] + ay[1] + ay[2] + ay[3]) * 0.25f + bg.y);
  }
}

// ---------------------------------------------------------------------------
// ucontrib[e,b,o] = xmean[e,b,:] . W_comb_right[o,:]   (no bias) fp32
// ---------------------------------------------------------------------------
__global__ __launch_bounds__(512, 4) void ucontrib_kernel(
    const float* __restrict__ xmean, const float* __restrict__ WtR,
    float* __restrict__ uc) {
  __shared__ float lw[D_ * D_];
  const int tid = threadIdx.x;
  for (int i = tid * 4; i < D_ * D_; i += 2048)
    *(float4*)&lw[i] = *(const float4*)&WtR[i];
  __syncthreads();

  const int wave = tid >> 6, lane = tid & 63;
  const int o2 = lane * 2;

  for (int pp = 0; pp < 8; ++pp) {
    const int pair = blockIdx.x * 64 + wave * 8 + pp;
    const float* __restrict__ xr = xmean + (size_t)pair * D_;
    float ax = 0, ay = 0;
#pragma unroll
    for (int dd = 0; dd < D_; dd += 4) {
      const float4 a = *(const float4*)&xr[dd];
      const float2 w0 = *(const float2*)&lw[(dd + 0) * D_ + o2];
      const float2 w1 = *(const float2*)&lw[(dd + 1) * D_ + o2];
      const float2 w2 = *(const float2*)&lw[(dd + 2) * D_ + o2];
      const float2 w3 = *(const float2*)&lw[(dd + 3) * D_ + o2];
      ax += a.x * w0.x; ay += a.x * w0.y;
      ax += a.y * w1.x; ay += a.y * w1.y;
      ax += a.z * w2.x; ay += a.z * w2.y;
      ax += a.w * w3.x; ay += a.w * w3.y;
    }
    *(float2*)&uc[(size_t)pair * D_ + o2] = make_float2(ax, ay);
  }
}

// ---------------------------------------------------------------------------
// feats (MFMA): out[r][o] = feats[r][:] . Wcomb_left[o][:] + bp[o]
// 3x bf16-split emulation of fp32. 16x16x32 MFMA, verified layouts:
//   A: lane l -> row = l&15, k = (l>>4)*8 + j (j=0..7)
//   B: lane l -> col = l&15, k = (l>>4)*8 + j
//   D: lane l, reg i -> col = l&15, row = (l>>4)*4 + i
// Block 512 thr = 8 waves; each wave 2 groups of 16 rows; grid 1152 blocks.
// B fragments (hi+lo = whole 128x128 W) staged in 64KB LDS -> 2 blocks/CU.
// ---------------------------------------------------------------------------
__global__ __launch_bounds__(512, 4) void feats_mfma_kernel(
    const float* __restrict__ feats, const ushort* __restrict__ Bpack,
    const float* __restrict__ bp, float* __restrict__ out_feats) {
  __shared__ bf16x8 ldsB[4096];  // 64 frags x 64 lanes, 16B each = 64KB
  const int tid = threadIdx.x;
  {
    const bf16x8* src = (const bf16x8*)Bpack;
    for (int i = tid; i < 4096; i += 512) ldsB[i] = src[i];
  }
  __syncthreads();

  const int wave = tid >> 6, lane = tid & 63;
  const int l15 = lane & 15;
  const int lh = (lane >> 4) & 3;   // 0..3
  // bias per output column (col = l&15 within n0-tile)
  float bp8[8];
#pragma unroll
  for (int n0 = 0; n0 < 8; ++n0) bp8[n0] = bp[n0 * 16 + l15];

  for (int g = 0; g < 2; ++g) {
    const int r0 = blockIdx.x * 256 + (wave + 8 * g) * 16;
    f32x4 acc[8];
#pragma unroll
    for (int n0 = 0; n0 < 8; ++n0) {
      acc[n0][0] = bp8[n0]; acc[n0][1] = bp8[n0];
      acc[n0][2] = bp8[n0]; acc[n0][3] = bp8[n0];
    }
    const float* __restrict__ arow = feats + (size_t)(r0 + l15) * D_ + lh * 8;
#pragma unroll
    for (int k0 = 0; k0 < 4; ++k0) {
      const float4 a0 = *(const float4*)(arow + k0 * 32);
      const float4 a1 = *(const float4*)(arow + k0 * 32 + 4);
      const float xs[8] = {a0.x, a0.y, a0.z, a0.w, a1.x, a1.y, a1.z, a1.w};
      BF8 ah, al;
#pragma unroll
      for (int j = 0; j < 8; ++j) {
        const ushort h = f2bf(xs[j]);
        ah.u[j] = h;
        al.u[j] = f2bf(xs[j] - bf2f(h));
      }
#pragma unroll
      for (int n0 = 0; n0 < 8; ++n0) {
        const bf16x8 bh = ldsB[(0 * 32 + k0 * 8 + n0) * 64 + lane];
        const bf16x8 bl = ldsB[(1 * 32 + k0 * 8 + n0) * 64 + lane];
        acc[n0] = __builtin_amdgcn_mfma_f32_16x16x32_bf16(ah.v, bh, acc[n0], 0, 0, 0);
        acc[n0] = __builtin_amdgcn_mfma_f32_16x16x32_bf16(al.v, bh, acc[n0], 0, 0, 0);
        acc[n0] = __builtin_amdgcn_mfma_f32_16x16x32_bf16(ah.v, bl, acc[n0], 0, 0, 0);
      }
    }
    const int rb = r0 + lh * 4;
#pragma unroll
    for (int n0 = 0; n0 < 8; ++n0) {
      const int ocol = n0 * 16 + l15;
#pragma unroll
      for (int i = 0; i < 4; ++i)
        out_feats[(size_t)(rb + i) * D_ + ocol] = acc[n0][i];
    }
  }
}

// ---------------------------------------------------------------------------
// fixup: winner rows get bias bcomb + uc instead of bp:
//   out_feats[cell*2+b][o] += uc[(e*2+b)][o] + bcomb[o] - bp[o]
// grid: E blocks x 256 thr; exactly one block acts per winner cell.
// ---------------------------------------------------------------------------
__global__ __launch_bounds__(256) void fixup_kernel(
    const int* __restrict__ nodes, const int* __restrict__ winner,
    const float* __restrict__ uc, const float* __restrict__ bcomb,
    const float* __restrict__ bp, float* __restrict__ out_feats) {
  const int e = blockIdx.x;
  const int n0 = nodes[e * 2 + 0] - 1;
  const int n1 = nodes[e * 2 + 1] - 1;
  const int cell = n0 * N_ + n1;
  if (winner[cell] != e) return;
  const int t = threadIdx.x;
  const int b = t >> 7, o = t & 127;
  out_feats[((size_t)cell * 2 + b) * D_ + o] +=
      uc[((size_t)e * 2 + b) * D_ + o] + bcomb[o] - bp[o];
}

// ---------------------------------------------------------------------------
// gather_add: out_x[t,e,b,:] += out_feats[n0-1, n1-1, b, :]
// ---------------------------------------------------------------------------
__global__ __launch_bounds__(256) void gather_add_kernel(
    const int* __restrict__ nodes, const float* __restrict__ out_feats,
    float* __restrict__ out_x) {
  const int e = blockIdx.x;
  const int tid = threadIdx.x;
  const int b = tid >> 7, o = tid & 127;
  const int n0 = nodes[((size_t)b * E_ + e) * 2 + 0] - 1;
  const int n1 = nodes[((size_t)b * E_ + e) * 2 + 1] - 1;
  const float fs = out_feats[(((size_t)n0 * N_ + n1) * B_ + b) * D_ + o];
#pragma unroll
  for (int t = 0; t < T_; ++t)
    out_x[(((size_t)t * E_ + e) * B_ + b) * D_ + o] += fs;
}

// ---------------------------------------------------------------------------
extern "C" void kernel_launch(void* const* d_in, const int* in_sizes, int n_in,
                              void* d_out, int out_size, void* d_ws, size_t ws_size,
                              hipStream_t stream) {
  const float* x      = (const float*)d_in[0];
  const float* feats  = (const float*)d_in[1];
  const int*   nodes  = (const int*)d_in[2];
  // d_in[3], d_in[4]: padding masks (unused by reference math)
  const float* pad    = (const float*)d_in[5];
  const float* W_g    = (const float*)d_in[6];
  const float* b_g    = (const float*)d_in[7];
  const float* W_lin  = (const float*)d_in[8];
  const float* b_lin  = (const float*)d_in[9];
  const float* W_f    = (const float*)d_in[10];
  const float* b_f    = (const float*)d_in[11];

  float* out_x     = (float*)d_out;                       // T*E*B*D
  float* out_feats = out_x + (size_t)T_ * E_ * B_ * D_;   // N*N*B*D

  if (ws_size < WS_FLOATS * sizeof(float) + 16) return;

  float*  wsf   = (float*)d_ws;
  float*  WtG   = wsf + OFF_WTG;
  float*  WtL   = wsf + OFF_WTL;
  float*  WtR   = wsf + OFF_WTR;
  float*  bcomb = wsf + OFF_BCOMB;
  float*  bpv   = wsf + OFF_BP;
  float*  xmean = wsf + OFF_XMEAN;
  float*  uc    = wsf + OFF_UC;
  int*    win   = (int*)(wsf + OFF_WIN);
  ushort* Bpack = (ushort*)(wsf + OFF_BPACK);

  prep_kernel<<<dim3(128), dim3(256), 0, stream>>>(W_f, W_lin, W_g, b_lin, b_f,
                                                   pad, WtG, WtL, WtR, bcomb,
                                                   bpv, win);
  prep2_kernel<<<dim3(64), dim3(64), 0, stream>>>(WtL, Bpack);
  scatter_kernel<<<dim3(E_ / 256), dim3(256), 0, stream>>>(nodes, win);
  gemm1_kernel<<<dim3(EB / 64), dim3(512), 0, stream>>>(x, WtG, b_g, out_x,
                                                        xmean);
  ucontrib_kernel<<<dim3(EB / 64), dim3(512), 0, stream>>>(xmean, WtR, uc);
  feats_mfma_kernel<<<dim3(NROWS / 256), dim3(512), 0, stream>>>(
      feats, Bpack, bpv, out_feats);
  fixup_kernel<<<dim3(E_), dim3(256), 0, stream>>>(nodes, win, uc, bcomb, bpv,
                                                   out_feats);
  gather_add_kernel<<<dim3(E_), dim3(256), 0, stream>>>(nodes, out_feats,
                                                        out_x);
}

// Round 4
// 694.896 us; speedup vs baseline: 2.0390x; 2.0390x over previous
//
#include <hip/hip_runtime.h>
#include <hip/hip_bf16.h>

// R3. Bench R2: PASSED, 1417us. gemm1 (fp32, wave-uniform broadcast loads,
// 128 blocks) = 693us/dispatch, FETCH 768MB (46x over-fetch), VALUBusy 1.4%,
// occ 10.7% -> uniform-address loads + tiny grid are pathological.
// Fix: gemm1/ucontrib -> generic row-tiled MFMA kernel cloning the verified
// feats_mfma structure (classic coalesced loads, 512/128 blocks), plus a
// tiny coalesced mean kernel. feats_mfma unchanged (need its counters).

constexpr int T_ = 4, E_ = 4096, B_ = 2, D_ = 128, N_ = 384;
constexpr int EB = E_ * B_;                  // 8192 (e,b) pairs
constexpr int XROWS = T_ * EB;               // 32768 rows of x
constexpr int NROWS = N_ * N_ * B_;          // 294912 feats rows
constexpr int NCELLS = N_ * N_;              // 147456

typedef __attribute__((ext_vector_type(8))) short bf16x8;
typedef __attribute__((ext_vector_type(4))) float f32x4;
union BF8 { bf16x8 v; ushort u[8]; };

// workspace layout (float element offsets)
constexpr size_t OFF_WTG    = 0;                              // 16384
constexpr size_t OFF_WTL    = 16384;                          // 16384
constexpr size_t OFF_WTR    = 32768;                          // 16384
constexpr size_t OFF_BCOMB  = 49152;                          // 128
constexpr size_t OFF_BP     = 49280;                          // 128
constexpr size_t OFF_XMEAN  = 49408;                          // EB*D
constexpr size_t OFF_UC     = OFF_XMEAN + (size_t)EB * D_;    // EB*D
constexpr size_t OFF_WIN    = OFF_UC + (size_t)EB * D_;       // N*N ints
constexpr size_t OFF_BPACK  = OFF_WIN + (size_t)NCELLS;       // 16384 (64KB)
constexpr size_t OFF_BPACKG = OFF_BPACK + 16384;              // 16384
constexpr size_t OFF_BPACKR = OFF_BPACKG + 16384;             // 16384
constexpr size_t WS_FLOATS  = OFF_BPACKR + 16384;             // ~9.5MB

static __device__ inline ushort f2bf(float x) {
  const uint u = __float_as_uint(x);
  return (ushort)((u + 0x7fffu + ((u >> 16) & 1u)) >> 16);
}
static __device__ inline float bf2f(ushort h) {
  return __uint_as_float(((uint)h) << 16);
}

// ---------------------------------------------------------------------------
// prep: W_comb halves (transposed), W_g transpose, bcomb, bp, winner init
// ---------------------------------------------------------------------------
__global__ __launch_bounds__(256) void prep_kernel(
    const float* __restrict__ W_f, const float* __restrict__ W_lin,
    const float* __restrict__ W_g, const float* __restrict__ b_lin,
    const float* __restrict__ b_f, const float* __restrict__ pad,
    float* __restrict__ WtG, float* __restrict__ WtL, float* __restrict__ WtR,
    float* __restrict__ bcomb, float* __restrict__ bp, int* __restrict__ winner) {
  const int o = blockIdx.x;    // 0..127
  const int c = threadIdx.x;   // 0..255

  for (int i = blockIdx.x * 256 + c; i < NCELLS; i += 128 * 256) winner[i] = -1;

  float acc = 0.f;
#pragma unroll 4
  for (int d = 0; d < D_; ++d) acc += W_f[o * D_ + d] * W_lin[d * (2 * D_) + c];

  if (c < D_) {
    WtL[c * D_ + o] = acc;
    WtG[c * D_ + o] = W_g[o * D_ + c];
  } else {
    WtR[(c - D_) * D_ + o] = acc;
  }

  __shared__ float red[256];
  red[c] = (c >= D_) ? acc : 0.f;
  __syncthreads();
  for (int s = 128; s > 0; s >>= 1) {
    if (c < s) red[c] += red[c + s];
    __syncthreads();
  }
  const float padsum = red[0];
  __syncthreads();
  red[c] = (c < D_) ? W_f[o * D_ + c] * b_lin[c] : 0.f;
  __syncthreads();
  for (int s = 128; s > 0; s >>= 1) {
    if (c < s) red[c] += red[c + s];
    __syncthreads();
  }
  if (c == 0) {
    const float bc = b_f[o] + red[0];
    bcomb[o] = bc;
    bp[o] = bc + pad[0] * padsum;
  }
}

// ---------------------------------------------------------------------------
// prep2: pack a [k][n] fp32 weight (128x128) into bf16 hi/lo MFMA B-fragment
// per-lane order. Frag fi = hi*32 + k0*8 + n0; lane l: n = n0*16 + (l&15),
// k = k0*32 + (l>>4)*8 + j.  grid: 64 blocks x 64 threads.
// ---------------------------------------------------------------------------
__global__ __launch_bounds__(64) void prep2_kernel(
    const float* __restrict__ Wkn, ushort* __restrict__ Bpack) {
  const int fi = blockIdx.x;          // 0..63
  const int l = threadIdx.x;          // 0..63
  const int ishi = (fi >> 5) ^ 1;     // fi<32 -> hi
  const int k0 = (fi >> 3) & 3;
  const int n0 = fi & 7;
  const int o = n0 * 16 + (l & 15);
  const int kb = k0 * 32 + ((l >> 4) & 3) * 8;
  ushort* dst = Bpack + ((size_t)fi * 64 + l) * 8;
#pragma unroll
  for (int j = 0; j < 8; ++j) {
    const float w = Wkn[(size_t)(kb + j) * D_ + o];
    const ushort h = f2bf(w);
    if (ishi) {
      dst[j] = h;
    } else {
      dst[j] = f2bf(w - bf2f(h));
    }
  }
}

// ---------------------------------------------------------------------------
// scatter: last-e-wins per grid cell (deterministic via atomicMax on e)
// ---------------------------------------------------------------------------
__global__ __launch_bounds__(256) void scatter_kernel(
    const int* __restrict__ nodes, int* __restrict__ winner) {
  const int e = blockIdx.x * 256 + threadIdx.x;
  if (e < E_) {
    const int n0 = nodes[e * 2 + 0];
    const int n1 = nodes[e * 2 + 1];
    atomicMax(&winner[(n0 - 1) * N_ + (n1 - 1)], e);
  }
}

// ---------------------------------------------------------------------------
// generic row-tiled MFMA GEMM: out[r][o] = A[r][:] . B[:][o] + bias[o]
// A row-major [rows][128], B packed by prep2 (hi/lo split), fp32 out.
// 256 thr = 4 waves, wave owns 16 rows; grid = rows/64.
// Verified fragment layouts (same as feats_mfma, passed R2):
//   A: lane l -> row=l&15, k=(l>>4)*8+j ; D: lane l,reg i -> col=l&15,
//   row=(l>>4)*4+i.
// ---------------------------------------------------------------------------
__global__ __launch_bounds__(256, 2) void rows_mfma_kernel(
    const float* __restrict__ A, const ushort* __restrict__ Bpack,
    const float* __restrict__ bias, float* __restrict__ out) {
  __shared__ bf16x8 ldsB[4096];  // 64 frags x 64 lanes x 16B = 64KB
  const int tid = threadIdx.x;
  {
    const bf16x8* src = (const bf16x8*)Bpack;
    for (int i = tid; i < 4096; i += 256) ldsB[i] = src[i];
  }
  __syncthreads();

  const int wave = tid >> 6, lane = tid & 63;
  const int l15 = lane & 15;
  const int lh = (lane >> 4) & 3;

  float bs8[8];
#pragma unroll
  for (int n0 = 0; n0 < 8; ++n0) bs8[n0] = bias ? bias[n0 * 16 + l15] : 0.f;

  const int r0 = blockIdx.x * 64 + wave * 16;
  f32x4 acc[8];
#pragma unroll
  for (int n0 = 0; n0 < 8; ++n0) {
    acc[n0][0] = bs8[n0]; acc[n0][1] = bs8[n0];
    acc[n0][2] = bs8[n0]; acc[n0][3] = bs8[n0];
  }
  const float* __restrict__ arow = A + (size_t)(r0 + l15) * D_ + lh * 8;
#pragma unroll
  for (int k0 = 0; k0 < 4; ++k0) {
    const float4 a0 = *(const float4*)(arow + k0 * 32);
    const float4 a1 = *(const float4*)(arow + k0 * 32 + 4);
    const float xs[8] = {a0.x, a0.y, a0.z, a0.w, a1.x, a1.y, a1.z, a1.w};
    BF8 ah, al;
#pragma unroll
    for (int j = 0; j < 8; ++j) {
      const ushort h = f2bf(xs[j]);
      ah.u[j] = h;
      al.u[j] = f2bf(xs[j] - bf2f(h));
    }
#pragma unroll
    for (int n0 = 0; n0 < 8; ++n0) {
      const bf16x8 bh = ldsB[(0 * 32 + k0 * 8 + n0) * 64 + lane];
      const bf16x8 bl = ldsB[(1 * 32 + k0 * 8 + n0) * 64 + lane];
      acc[n0] = __builtin_amdgcn_mfma_f32_16x16x32_bf16(ah.v, bh, acc[n0], 0, 0, 0);
      acc[n0] = __builtin_amdgcn_mfma_f32_16x16x32_bf16(al.v, bh, acc[n0], 0, 0, 0);
      acc[n0] = __builtin_amdgcn_mfma_f32_16x16x32_bf16(ah.v, bl, acc[n0], 0, 0, 0);
    }
  }
  const int rb = r0 + lh * 4;
#pragma unroll
  for (int n0 = 0; n0 < 8; ++n0) {
    const int ocol = n0 * 16 + l15;
#pragma unroll
    for (int i = 0; i < 4; ++i)
      out[(size_t)(rb + i) * D_ + ocol] = acc[n0][i];
  }
}

// ---------------------------------------------------------------------------
// mean over t: xmean[pair][o] = 0.25 * sum_t out_x[t*EB + pair][o]
// 1024 blocks x 256 thr, float4 per thread, fully coalesced.
// ---------------------------------------------------------------------------
__global__ __launch_bounds__(256) void mean_kernel(
    const float* __restrict__ out_x, float* __restrict__ xmean) {
  const int idx = blockIdx.x * 256 + threadIdx.x;   // 0 .. EB*32-1
  const int pair = idx >> 5;
  const int o4 = (idx & 31) * 4;
  const size_t base = (size_t)pair * D_ + o4;
  float4 s = *(const float4*)&out_x[base];
  const float4 v1 = *(const float4*)&out_x[base + (size_t)1 * EB * D_];
  const float4 v2 = *(const float4*)&out_x[base + (size_t)2 * EB * D_];
  const float4 v3 = *(const float4*)&out_x[base + (size_t)3 * EB * D_];
  s.x = (s.x + v1.x + v2.x + v3.x) * 0.25f;
  s.y = (s.y + v1.y + v2.y + v3.y) * 0.25f;
  s.z = (s.z + v1.z + v2.z + v3.z) * 0.25f;
  s.w = (s.w + v1.w + v2.w + v3.w) * 0.25f;
  *(float4*)&xmean[base] = s;
}

// ---------------------------------------------------------------------------
// feats (MFMA): out[r][o] = feats[r][:] . Wcomb_left[:][o] + bp[o]
// (unchanged from R2 — passed; counters next round will drive its tuning)
// ---------------------------------------------------------------------------
__global__ __launch_bounds__(512, 4) void feats_mfma_kernel(
    const float* __restrict__ feats, const ushort* __restrict__ Bpack,
    const float* __restrict__ bp, float* __restrict__ out_feats) {
  __shared__ bf16x8 ldsB[4096];  // 64KB
  const int tid = threadIdx.x;
  {
    const bf16x8* src = (const bf16x8*)Bpack;
    for (int i = tid; i < 4096; i += 512) ldsB[i] = src[i];
  }
  __syncthreads();

  const int wave = tid >> 6, lane = tid & 63;
  const int l15 = lane & 15;
  const int lh = (lane >> 4) & 3;
  float bp8[8];
#pragma unroll
  for (int n0 = 0; n0 < 8; ++n0) bp8[n0] = bp[n0 * 16 + l15];

  for (int g = 0; g < 2; ++g) {
    const int r0 = blockIdx.x * 256 + (wave + 8 * g) * 16;
    f32x4 acc[8];
#pragma unroll
    for (int n0 = 0; n0 < 8; ++n0) {
      acc[n0][0] = bp8[n0]; acc[n0][1] = bp8[n0];
      acc[n0][2] = bp8[n0]; acc[n0][3] = bp8[n0];
    }
    const float* __restrict__ arow = feats + (size_t)(r0 + l15) * D_ + lh * 8;
#pragma unroll
    for (int k0 = 0; k0 < 4; ++k0) {
      const float4 a0 = *(const float4*)(arow + k0 * 32);
      const float4 a1 = *(const float4*)(arow + k0 * 32 + 4);
      const float xs[8] = {a0.x, a0.y, a0.z, a0.w, a1.x, a1.y, a1.z, a1.w};
      BF8 ah, al;
#pragma unroll
      for (int j = 0; j < 8; ++j) {
        const ushort h = f2bf(xs[j]);
        ah.u[j] = h;
        al.u[j] = f2bf(xs[j] - bf2f(h));
      }
#pragma unroll
      for (int n0 = 0; n0 < 8; ++n0) {
        const bf16x8 bh = ldsB[(0 * 32 + k0 * 8 + n0) * 64 + lane];
        const bf16x8 bl = ldsB[(1 * 32 + k0 * 8 + n0) * 64 + lane];
        acc[n0] = __builtin_amdgcn_mfma_f32_16x16x32_bf16(ah.v, bh, acc[n0], 0, 0, 0);
        acc[n0] = __builtin_amdgcn_mfma_f32_16x16x32_bf16(al.v, bh, acc[n0], 0, 0, 0);
        acc[n0] = __builtin_amdgcn_mfma_f32_16x16x32_bf16(ah.v, bl, acc[n0], 0, 0, 0);
      }
    }
    const int rb = r0 + lh * 4;
#pragma unroll
    for (int n0 = 0; n0 < 8; ++n0) {
      const int ocol = n0 * 16 + l15;
#pragma unroll
      for (int i = 0; i < 4; ++i)
        out_feats[(size_t)(rb + i) * D_ + ocol] = acc[n0][i];
    }
  }
}

// ---------------------------------------------------------------------------
// fixup: winner rows: out_feats[cell*2+b][o] += uc[e*2+b][o] + bcomb[o]-bp[o]
// ---------------------------------------------------------------------------
__global__ __launch_bounds__(256) void fixup_kernel(
    const int* __restrict__ nodes, const int* __restrict__ winner,
    const float* __restrict__ uc, const float* __restrict__ bcomb,
    const float* __restrict__ bp, float* __restrict__ out_feats) {
  const int e = blockIdx.x;
  const int n0 = nodes[e * 2 + 0] - 1;
  const int n1 = nodes[e * 2 + 1] - 1;
  const int cell = n0 * N_ + n1;
  if (winner[cell] != e) return;
  const int t = threadIdx.x;
  const int b = t >> 7, o = t & 127;
  out_feats[((size_t)cell * 2 + b) * D_ + o] +=
      uc[((size_t)e * 2 + b) * D_ + o] + bcomb[o] - bp[o];
}

// ---------------------------------------------------------------------------
// gather_add: out_x[t,e,b,:] += out_feats[n0-1, n1-1, b, :]
// ---------------------------------------------------------------------------
__global__ __launch_bounds__(256) void gather_add_kernel(
    const int* __restrict__ nodes, const float* __restrict__ out_feats,
    float* __restrict__ out_x) {
  const int e = blockIdx.x;
  const int tid = threadIdx.x;
  const int b = tid >> 7, o = tid & 127;
  const int n0 = nodes[((size_t)b * E_ + e) * 2 + 0] - 1;
  const int n1 = nodes[((size_t)b * E_ + e) * 2 + 1] - 1;
  const float fs = out_feats[(((size_t)n0 * N_ + n1) * B_ + b) * D_ + o];
#pragma unroll
  for (int t = 0; t < T_; ++t)
    out_x[(((size_t)t * E_ + e) * B_ + b) * D_ + o] += fs;
}

// ---------------------------------------------------------------------------
extern "C" void kernel_launch(void* const* d_in, const int* in_sizes, int n_in,
                              void* d_out, int out_size, void* d_ws, size_t ws_size,
                              hipStream_t stream) {
  const float* x      = (const float*)d_in[0];
  const float* feats  = (const float*)d_in[1];
  const int*   nodes  = (const int*)d_in[2];
  const float* pad    = (const float*)d_in[5];
  const float* W_g    = (const float*)d_in[6];
  const float* b_g    = (const float*)d_in[7];
  const float* W_lin  = (const float*)d_in[8];
  const float* b_lin  = (const float*)d_in[9];
  const float* W_f    = (const float*)d_in[10];
  const float* b_f    = (const float*)d_in[11];

  float* out_x     = (float*)d_out;                       // T*E*B*D
  float* out_feats = out_x + (size_t)T_ * E_ * B_ * D_;   // N*N*B*D

  if (ws_size < WS_FLOATS * sizeof(float) + 16) return;

  float*  wsf    = (float*)d_ws;
  float*  WtG    = wsf + OFF_WTG;
  float*  WtL    = wsf + OFF_WTL;
  float*  WtR    = wsf + OFF_WTR;
  float*  bcomb  = wsf + OFF_BCOMB;
  float*  bpv    = wsf + OFF_BP;
  float*  xmean  = wsf + OFF_XMEAN;
  float*  uc     = wsf + OFF_UC;
  int*    win    = (int*)(wsf + OFF_WIN);
  ushort* Bpack  = (ushort*)(wsf + OFF_BPACK);
  ushort* BpackG = (ushort*)(wsf + OFF_BPACKG);
  ushort* BpackR = (ushort*)(wsf + OFF_BPACKR);

  prep_kernel<<<dim3(128), dim3(256), 0, stream>>>(W_f, W_lin, W_g, b_lin, b_f,
                                                   pad, WtG, WtL, WtR, bcomb,
                                                   bpv, win);
  prep2_kernel<<<dim3(64), dim3(64), 0, stream>>>(WtL, Bpack);
  prep2_kernel<<<dim3(64), dim3(64), 0, stream>>>(WtG, BpackG);
  prep2_kernel<<<dim3(64), dim3(64), 0, stream>>>(WtR, BpackR);
  scatter_kernel<<<dim3(E_ / 256), dim3(256), 0, stream>>>(nodes, win);

  // x1 = x @ W_g^T + b_g   (32768 rows)
  rows_mfma_kernel<<<dim3(XROWS / 64), dim3(256), 0, stream>>>(x, BpackG, b_g,
                                                               out_x);
  mean_kernel<<<dim3(EB * 32 / 256), dim3(256), 0, stream>>>(out_x, xmean);
  // uc = xmean @ Wcomb_right^T   (8192 rows)
  rows_mfma_kernel<<<dim3(EB / 64), dim3(256), 0, stream>>>(xmean, BpackR,
                                                            nullptr, uc);
  feats_mfma_kernel<<<dim3(NROWS / 256), dim3(512), 0, stream>>>(
      feats, Bpack, bpv, out_feats);
  fixup_kernel<<<dim3(E_), dim3(256), 0, stream>>>(nodes, win, uc, bcomb, bpv,
                                                   out_feats);
  gather_add_kernel<<<dim3(E_), dim3(256), 0, stream>>>(nodes, out_feats,
                                                        out_x);
}

// Round 5
// 400.797 us; speedup vs baseline: 3.5351x; 1.7338x over previous
//
#include <hip/hip_runtime.h>
#include <hip/hip_bf16.h>

// R4. Bench R3: PASSED 695us. feats_mfma = 421us, FETCH 594MB WRITE 666MB
// (4.3x ideal 302MB), HBM 38%, Mfma/VALU ~2.5% -> pure memory pathology from
// fragment-shaped per-lane global accesses (16B/32B-stride reads, 4B scatter
// stores). Fix: one tile_mfma template, classic LDS staging:
//   coalesced float4 global reads -> XOR-swizzled 32KB LDS tile ->
//   ds_read_b128 fragments -> MFMA -> acc transposed via same LDS ->
//   fully coalesced float4 stores. B-frags read per-k0 from L2-hot Bpack.
// Replaces rows_mfma + feats_mfma. Everything else unchanged (passed).

constexpr int T_ = 4, E_ = 4096, B_ = 2, D_ = 128, N_ = 384;
constexpr int EB = E_ * B_;                  // 8192 (e,b) pairs
constexpr int XROWS = T_ * EB;               // 32768 rows of x
constexpr int NROWS = N_ * N_ * B_;          // 294912 feats rows
constexpr int NCELLS = N_ * N_;              // 147456

typedef __attribute__((ext_vector_type(8))) short bf16x8;
typedef __attribute__((ext_vector_type(4))) float f32x4;
union BF8 { bf16x8 v; ushort u[8]; };

// workspace layout (float element offsets)
constexpr size_t OFF_WTG    = 0;                              // 16384
constexpr size_t OFF_WTL    = 16384;                          // 16384
constexpr size_t OFF_WTR    = 32768;                          // 16384
constexpr size_t OFF_BCOMB  = 49152;                          // 128
constexpr size_t OFF_BP     = 49280;                          // 128
constexpr size_t OFF_XMEAN  = 49408;                          // EB*D
constexpr size_t OFF_UC     = OFF_XMEAN + (size_t)EB * D_;    // EB*D
constexpr size_t OFF_WIN    = OFF_UC + (size_t)EB * D_;       // N*N ints
constexpr size_t OFF_BPACK  = OFF_WIN + (size_t)NCELLS;       // 16384 (64KB)
constexpr size_t OFF_BPACKG = OFF_BPACK + 16384;              // 16384
constexpr size_t OFF_BPACKR = OFF_BPACKG + 16384;             // 16384
constexpr size_t WS_FLOATS  = OFF_BPACKR + 16384;             // ~9.5MB

static __device__ inline ushort f2bf(float x) {
  const uint u = __float_as_uint(x);
  return (ushort)((u + 0x7fffu + ((u >> 16) & 1u)) >> 16);
}
static __device__ inline float bf2f(ushort h) {
  return __uint_as_float(((uint)h) << 16);
}

// ---------------------------------------------------------------------------
// prep: W_comb halves (transposed), W_g transpose, bcomb, bp, winner init
// ---------------------------------------------------------------------------
__global__ __launch_bounds__(256) void prep_kernel(
    const float* __restrict__ W_f, const float* __restrict__ W_lin,
    const float* __restrict__ W_g, const float* __restrict__ b_lin,
    const float* __restrict__ b_f, const float* __restrict__ pad,
    float* __restrict__ WtG, float* __restrict__ WtL, float* __restrict__ WtR,
    float* __restrict__ bcomb, float* __restrict__ bp, int* __restrict__ winner) {
  const int o = blockIdx.x;    // 0..127
  const int c = threadIdx.x;   // 0..255

  for (int i = blockIdx.x * 256 + c; i < NCELLS; i += 128 * 256) winner[i] = -1;

  float acc = 0.f;
#pragma unroll 4
  for (int d = 0; d < D_; ++d) acc += W_f[o * D_ + d] * W_lin[d * (2 * D_) + c];

  if (c < D_) {
    WtL[c * D_ + o] = acc;
    WtG[c * D_ + o] = W_g[o * D_ + c];
  } else {
    WtR[(c - D_) * D_ + o] = acc;
  }

  __shared__ float red[256];
  red[c] = (c >= D_) ? acc : 0.f;
  __syncthreads();
  for (int s = 128; s > 0; s >>= 1) {
    if (c < s) red[c] += red[c + s];
    __syncthreads();
  }
  const float padsum = red[0];
  __syncthreads();
  red[c] = (c < D_) ? W_f[o * D_ + c] * b_lin[c] : 0.f;
  __syncthreads();
  for (int s = 128; s > 0; s >>= 1) {
    if (c < s) red[c] += red[c + s];
    __syncthreads();
  }
  if (c == 0) {
    const float bc = b_f[o] + red[0];
    bcomb[o] = bc;
    bp[o] = bc + pad[0] * padsum;
  }
}

// ---------------------------------------------------------------------------
// prep2: pack a [k][n] fp32 weight (128x128) into bf16 hi/lo MFMA B-fragment
// per-lane order. Frag fi = hi*32 + k0*8 + n0; lane l: n = n0*16 + (l&15),
// k = k0*32 + (l>>4)*8 + j.  grid: 64 blocks x 64 threads.
// ---------------------------------------------------------------------------
__global__ __launch_bounds__(64) void prep2_kernel(
    const float* __restrict__ Wkn, ushort* __restrict__ Bpack) {
  const int fi = blockIdx.x;          // 0..63
  const int l = threadIdx.x;          // 0..63
  const int ishi = (fi >> 5) ^ 1;     // fi<32 -> hi
  const int k0 = (fi >> 3) & 3;
  const int n0 = fi & 7;
  const int o = n0 * 16 + (l & 15);
  const int kb = k0 * 32 + ((l >> 4) & 3) * 8;
  ushort* dst = Bpack + ((size_t)fi * 64 + l) * 8;
#pragma unroll
  for (int j = 0; j < 8; ++j) {
    const float w = Wkn[(size_t)(kb + j) * D_ + o];
    const ushort h = f2bf(w);
    if (ishi) {
      dst[j] = h;
    } else {
      dst[j] = f2bf(w - bf2f(h));
    }
  }
}

// ---------------------------------------------------------------------------
// scatter: last-e-wins per grid cell (deterministic via atomicMax on e)
// ---------------------------------------------------------------------------
__global__ __launch_bounds__(256) void scatter_kernel(
    const int* __restrict__ nodes, int* __restrict__ winner) {
  const int e = blockIdx.x * 256 + threadIdx.x;
  if (e < E_) {
    const int n0 = nodes[e * 2 + 0];
    const int n1 = nodes[e * 2 + 1];
    atomicMax(&winner[(n0 - 1) * N_ + (n1 - 1)], e);
  }
}

// ---------------------------------------------------------------------------
// tile_mfma: out[r][o] = A[r][:] . Wpack[:][o] + bias[o]   (bias nullable)
// 256 thr = 4 waves; 64-row tile per block; grid = rows/64.
// LDS 32KB, XOR-swizzled (chunk ^= row&7 on 16B chunks) for bank balance.
// MFMA 16x16x32 bf16 hi/lo split (verified layouts, R2/R3 passed):
//   A: lane l -> row=l&15, k=(l>>4)*8+j ; D: lane l,reg i -> col=l&15,
//   row=(l>>4)*4+i.
// ---------------------------------------------------------------------------
__global__ __launch_bounds__(256) void tile_mfma_kernel(
    const float* __restrict__ A, const ushort* __restrict__ Bpack,
    const float* __restrict__ bias, float* __restrict__ out) {
  __shared__ float lw[64 * 128];   // 32 KB
  const int tid = threadIdx.x;
  const size_t tile0 = (size_t)blockIdx.x * 64;

  // stage A tile: fully coalesced float4 reads, swizzled LDS writes
#pragma unroll
  for (int j = 0; j < 8; ++j) {
    const int idx = j * 256 + tid;        // 0..2047
    const int row = idx >> 5;             // 0..63
    const int c4 = idx & 31;              // float4 chunk in row
    const float4 v = *(const float4*)&A[(tile0 + row) * D_ + c4 * 4];
    const int fidx = (row * 128 + c4 * 4) ^ ((row & 7) << 2);
    *(float4*)&lw[fidx] = v;
  }
  __syncthreads();

  const int wave = tid >> 6, lane = tid & 63;
  const int l15 = lane & 15;
  const int lh = (lane >> 4) & 3;
  const int arow = wave * 16 + l15;     // local row this lane's A-frag uses
  const int asw = (arow & 7) << 2;

  f32x4 acc[8];
#pragma unroll
  for (int n0 = 0; n0 < 8; ++n0) {
    const float b = bias ? bias[n0 * 16 + l15] : 0.f;
    acc[n0][0] = b; acc[n0][1] = b; acc[n0][2] = b; acc[n0][3] = b;
  }

  const bf16x8* __restrict__ bp8 = (const bf16x8*)Bpack;
#pragma unroll
  for (int k0 = 0; k0 < 4; ++k0) {
    const int base = arow * 128 + lh * 8 + k0 * 32;
    const float4 a0 = *(const float4*)&lw[(base + 0) ^ asw];
    const float4 a1 = *(const float4*)&lw[(base + 4) ^ asw];
    const float xs[8] = {a0.x, a0.y, a0.z, a0.w, a1.x, a1.y, a1.z, a1.w};
    BF8 ah, al;
#pragma unroll
    for (int j = 0; j < 8; ++j) {
      const ushort h = f2bf(xs[j]);
      ah.u[j] = h;
      al.u[j] = f2bf(xs[j] - bf2f(h));
    }
    // hi-B: ah*bh + al*bh
    bf16x8 bh[8];
#pragma unroll
    for (int n0 = 0; n0 < 8; ++n0)
      bh[n0] = bp8[(size_t)((0 * 32 + k0 * 8 + n0) * 64 + lane)];
#pragma unroll
    for (int n0 = 0; n0 < 8; ++n0) {
      acc[n0] = __builtin_amdgcn_mfma_f32_16x16x32_bf16(ah.v, bh[n0], acc[n0], 0, 0, 0);
      acc[n0] = __builtin_amdgcn_mfma_f32_16x16x32_bf16(al.v, bh[n0], acc[n0], 0, 0, 0);
    }
    // lo-B: ah*bl
    bf16x8 bl[8];
#pragma unroll
    for (int n0 = 0; n0 < 8; ++n0)
      bl[n0] = bp8[(size_t)((1 * 32 + k0 * 8 + n0) * 64 + lane)];
#pragma unroll
    for (int n0 = 0; n0 < 8; ++n0)
      acc[n0] = __builtin_amdgcn_mfma_f32_16x16x32_bf16(ah.v, bl[n0], acc[n0], 0, 0, 0);
  }

  // transpose acc through LDS (swizzled), then fully coalesced stores
  __syncthreads();
#pragma unroll
  for (int n0 = 0; n0 < 8; ++n0) {
    const int col = n0 * 16 + l15;
#pragma unroll
    for (int i = 0; i < 4; ++i) {
      const int row = wave * 16 + lh * 4 + i;
      lw[(row * 128 + col) ^ ((row & 7) << 2)] = acc[n0][i];
    }
  }
  __syncthreads();
#pragma unroll
  for (int j = 0; j < 8; ++j) {
    const int idx = j * 256 + tid;
    const int row = idx >> 5;
    const int c4 = idx & 31;
    const float4 v = *(const float4*)&lw[(row * 128 + c4 * 4) ^ ((row & 7) << 2)];
    *(float4*)&out[(tile0 + row) * D_ + c4 * 4] = v;
  }
}

// ---------------------------------------------------------------------------
// mean over t: xmean[pair][o] = 0.25 * sum_t out_x[t*EB + pair][o]
// ---------------------------------------------------------------------------
__global__ __launch_bounds__(256) void mean_kernel(
    const float* __restrict__ out_x, float* __restrict__ xmean) {
  const int idx = blockIdx.x * 256 + threadIdx.x;   // 0 .. EB*32-1
  const int pair = idx >> 5;
  const int o4 = (idx & 31) * 4;
  const size_t base = (size_t)pair * D_ + o4;
  float4 s = *(const float4*)&out_x[base];
  const float4 v1 = *(const float4*)&out_x[base + (size_t)1 * EB * D_];
  const float4 v2 = *(const float4*)&out_x[base + (size_t)2 * EB * D_];
  const float4 v3 = *(const float4*)&out_x[base + (size_t)3 * EB * D_];
  s.x = (s.x + v1.x + v2.x + v3.x) * 0.25f;
  s.y = (s.y + v1.y + v2.y + v3.y) * 0.25f;
  s.z = (s.z + v1.z + v2.z + v3.z) * 0.25f;
  s.w = (s.w + v1.w + v2.w + v3.w) * 0.25f;
  *(float4*)&xmean[base] = s;
}

// ---------------------------------------------------------------------------
// fixup: winner rows: out_feats[cell*2+b][o] += uc[e*2+b][o] + bcomb[o]-bp[o]
// ---------------------------------------------------------------------------
__global__ __launch_bounds__(256) void fixup_kernel(
    const int* __restrict__ nodes, const int* __restrict__ winner,
    const float* __restrict__ uc, const float* __restrict__ bcomb,
    const float* __restrict__ bp, float* __restrict__ out_feats) {
  const int e = blockIdx.x;
  const int n0 = nodes[e * 2 + 0] - 1;
  const int n1 = nodes[e * 2 + 1] - 1;
  const int cell = n0 * N_ + n1;
  if (winner[cell] != e) return;
  const int t = threadIdx.x;
  const int b = t >> 7, o = t & 127;
  out_feats[((size_t)cell * 2 + b) * D_ + o] +=
      uc[((size_t)e * 2 + b) * D_ + o] + bcomb[o] - bp[o];
}

// ---------------------------------------------------------------------------
// gather_add: out_x[t,e,b,:] += out_feats[n0-1, n1-1, b, :]
// ---------------------------------------------------------------------------
__global__ __launch_bounds__(256) void gather_add_kernel(
    const int* __restrict__ nodes, const float* __restrict__ out_feats,
    float* __restrict__ out_x) {
  const int e = blockIdx.x;
  const int tid = threadIdx.x;
  const int b = tid >> 7, o = tid & 127;
  const int n0 = nodes[((size_t)b * E_ + e) * 2 + 0] - 1;
  const int n1 = nodes[((size_t)b * E_ + e) * 2 + 1] - 1;
  const float fs = out_feats[(((size_t)n0 * N_ + n1) * B_ + b) * D_ + o];
#pragma unroll
  for (int t = 0; t < T_; ++t)
    out_x[(((size_t)t * E_ + e) * B_ + b) * D_ + o] += fs;
}

// ---------------------------------------------------------------------------
extern "C" void kernel_launch(void* const* d_in, const int* in_sizes, int n_in,
                              void* d_out, int out_size, void* d_ws, size_t ws_size,
                              hipStream_t stream) {
  const float* x      = (const float*)d_in[0];
  const float* feats  = (const float*)d_in[1];
  const int*   nodes  = (const int*)d_in[2];
  const float* pad    = (const float*)d_in[5];
  const float* W_g    = (const float*)d_in[6];
  const float* b_g    = (const float*)d_in[7];
  const float* W_lin  = (const float*)d_in[8];
  const float* b_lin  = (const float*)d_in[9];
  const float* W_f    = (const float*)d_in[10];
  const float* b_f    = (const float*)d_in[11];

  float* out_x     = (float*)d_out;                       // T*E*B*D
  float* out_feats = out_x + (size_t)T_ * E_ * B_ * D_;   // N*N*B*D

  if (ws_size < WS_FLOATS * sizeof(float) + 16) return;

  float*  wsf    = (float*)d_ws;
  float*  WtG    = wsf + OFF_WTG;
  float*  WtL    = wsf + OFF_WTL;
  float*  WtR    = wsf + OFF_WTR;
  float*  bcomb  = wsf + OFF_BCOMB;
  float*  bpv    = wsf + OFF_BP;
  float*  xmean  = wsf + OFF_XMEAN;
  float*  uc     = wsf + OFF_UC;
  int*    win    = (int*)(wsf + OFF_WIN);
  ushort* Bpack  = (ushort*)(wsf + OFF_BPACK);
  ushort* BpackG = (ushort*)(wsf + OFF_BPACKG);
  ushort* BpackR = (ushort*)(wsf + OFF_BPACKR);

  prep_kernel<<<dim3(128), dim3(256), 0, stream>>>(W_f, W_lin, W_g, b_lin, b_f,
                                                   pad, WtG, WtL, WtR, bcomb,
                                                   bpv, win);
  prep2_kernel<<<dim3(64), dim3(64), 0, stream>>>(WtL, Bpack);
  prep2_kernel<<<dim3(64), dim3(64), 0, stream>>>(WtG, BpackG);
  prep2_kernel<<<dim3(64), dim3(64), 0, stream>>>(WtR, BpackR);
  scatter_kernel<<<dim3(E_ / 256), dim3(256), 0, stream>>>(nodes, win);

  // x1 = x @ W_g^T + b_g   (32768 rows)
  tile_mfma_kernel<<<dim3(XROWS / 64), dim3(256), 0, stream>>>(x, BpackG, b_g,
                                                               out_x);
  mean_kernel<<<dim3(EB * 32 / 256), dim3(256), 0, stream>>>(out_x, xmean);
  // uc = xmean @ Wcomb_right^T   (8192 rows)
  tile_mfma_kernel<<<dim3(EB / 64), dim3(256), 0, stream>>>(xmean, BpackR,
                                                            nullptr, uc);
  // feats2 = feats @ Wcomb_left^T + bp   (294912 rows)
  tile_mfma_kernel<<<dim3(NROWS / 64), dim3(256), 0, stream>>>(feats, Bpack,
                                                               bpv, out_feats);
  fixup_kernel<<<dim3(E_), dim3(256), 0, stream>>>(nodes, win, uc, bcomb, bpv,
                                                   out_feats);
  gather_add_kernel<<<dim3(E_), dim3(256), 0, stream>>>(nodes, out_feats,
                                                        out_x);
}